// Round 4
// baseline (82.046 us; speedup 1.0000x reference)
//
#include <hip/hip_runtime.h>
#include <math.h>

#define BATCH 384
#define FEAT 256
#define GROUP 8
// ANNEAL = 0.01 -> 1/temp = 100

__device__ __forceinline__ float temp_sigmoid_from_diff(float diff) {
    // reference: exponent = clip(-t/temp, -50, 50); 1/(1+exp(exponent))
    float e = fminf(fmaxf(-100.0f * diff, -50.0f), 50.0f);
    return 1.0f / (1.0f + __expf(e));
}

// ---------------------------------------------------------------------------
// One block per PAIR of query rows (i0 = 2*blockIdx, i1 = i0+1).
// Rows 2B and 2B+1 always share the same id-group (group = i>>3), so the
// block-diagonal base is common to both rows.
//
// Sim loop: 16-lane clusters, each wave covers 4 gallery rows/iter with
// contiguous 64B slices per lane (16 cache lines per load instruction).
// Each loaded gallery tile feeds BOTH rows' dot products plus one shared
// q = g.g accumulator -> per-row load count and norm redundancy halved
// vs the one-row-per-block version.
// ---------------------------------------------------------------------------
__global__ __launch_bounds__(256) void smoothap_main(
    const float* __restrict__ preds, const float* __restrict__ gallery,
    float* __restrict__ partials)
{
    __shared__ float s0[BATCH];              // sim row for query i0
    __shared__ float s1[BATCH];              // sim row for query i0+1
    __shared__ float rk2[2][GROUP];
    __shared__ float part[2][2][GROUP];      // [row][wave-half][b]

    const int i0   = blockIdx.x * 2;
    const int t    = threadIdx.x;
    const int wave = t >> 6;
    const int lane = t & 63;
    const int sub  = lane & 15;   // position within 16-lane cluster
    const int grp  = lane >> 4;   // which of the 4 rows this cluster serves

    // ---- p-hat for rows i0, i0+1: lane holds dims {sub*4 + 64*c}, c=0..3
    const float* pr = preds + i0 * FEAT + sub * 4;
    float4 p0 = *(const float4*)(pr);
    float4 p1 = *(const float4*)(pr + 64);
    float4 p2 = *(const float4*)(pr + 128);
    float4 p3 = *(const float4*)(pr + 192);
    float4 r0 = *(const float4*)(pr + 256);
    float4 r1 = *(const float4*)(pr + 320);
    float4 r2 = *(const float4*)(pr + 384);
    float4 r3 = *(const float4*)(pr + 448);

    float sqa = p0.x * p0.x + p0.y * p0.y + p0.z * p0.z + p0.w * p0.w
              + p1.x * p1.x + p1.y * p1.y + p1.z * p1.z + p1.w * p1.w
              + p2.x * p2.x + p2.y * p2.y + p2.z * p2.z + p2.w * p2.w
              + p3.x * p3.x + p3.y * p3.y + p3.z * p3.z + p3.w * p3.w;
    float sqb = r0.x * r0.x + r0.y * r0.y + r0.z * r0.z + r0.w * r0.w
              + r1.x * r1.x + r1.y * r1.y + r1.z * r1.z + r1.w * r1.w
              + r2.x * r2.x + r2.y * r2.y + r2.z * r2.z + r2.w * r2.w
              + r3.x * r3.x + r3.y * r3.y + r3.z * r3.z + r3.w * r3.w;
    sqa += __shfl_xor(sqa, 1, 64);  sqb += __shfl_xor(sqb, 1, 64);
    sqa += __shfl_xor(sqa, 2, 64);  sqb += __shfl_xor(sqb, 2, 64);
    sqa += __shfl_xor(sqa, 4, 64);  sqb += __shfl_xor(sqb, 4, 64);
    sqa += __shfl_xor(sqa, 8, 64);  sqb += __shfl_xor(sqb, 8, 64);
    const float pna = fmaxf(sqrtf(sqa), 1e-12f);
    const float pnb = fmaxf(sqrtf(sqb), 1e-12f);
    p0.x /= pna; p0.y /= pna; p0.z /= pna; p0.w /= pna;
    p1.x /= pna; p1.y /= pna; p1.z /= pna; p1.w /= pna;
    p2.x /= pna; p2.y /= pna; p2.z /= pna; p2.w /= pna;
    p3.x /= pna; p3.y /= pna; p3.z /= pna; p3.w /= pna;
    r0.x /= pnb; r0.y /= pnb; r0.z /= pnb; r0.w /= pnb;
    r1.x /= pnb; r1.y /= pnb; r1.z /= pnb; r1.w /= pnb;
    r2.x /= pnb; r2.y /= pnb; r2.z /= pnb; r2.w /= pnb;
    r3.x /= pnb; r3.y /= pnb; r3.z /= pnb; r3.w /= pnb;

    // ---- sim rows: wave w covers gallery rows [w*96, w*96+96), 4 per iter
    const int r_end = wave * 96 + 96;
    #pragma unroll 2
    for (int r = wave * 96; r < r_end; r += 4) {
        const float* g = gallery + (r + grp) * FEAT + sub * 4;
        float4 ga = *(const float4*)(g);
        float4 gb = *(const float4*)(g + 64);
        float4 gc = *(const float4*)(g + 128);
        float4 gd = *(const float4*)(g + 192);
        float q  = ga.x * ga.x + ga.y * ga.y + ga.z * ga.z + ga.w * ga.w
                 + gb.x * gb.x + gb.y * gb.y + gb.z * gb.z + gb.w * gb.w
                 + gc.x * gc.x + gc.y * gc.y + gc.z * gc.z + gc.w * gc.w
                 + gd.x * gd.x + gd.y * gd.y + gd.z * gd.z + gd.w * gd.w;
        float d0 = p0.x * ga.x + p0.y * ga.y + p0.z * ga.z + p0.w * ga.w
                 + p1.x * gb.x + p1.y * gb.y + p1.z * gb.z + p1.w * gb.w
                 + p2.x * gc.x + p2.y * gc.y + p2.z * gc.z + p2.w * gc.w
                 + p3.x * gd.x + p3.y * gd.y + p3.z * gd.z + p3.w * gd.w;
        float d1 = r0.x * ga.x + r0.y * ga.y + r0.z * ga.z + r0.w * ga.w
                 + r1.x * gb.x + r1.y * gb.y + r1.z * gb.z + r1.w * gb.w
                 + r2.x * gc.x + r2.y * gc.y + r2.z * gc.z + r2.w * gc.w
                 + r3.x * gd.x + r3.y * gd.y + r3.z * gd.z + r3.w * gd.w;
        d0 += __shfl_xor(d0, 1, 64); d1 += __shfl_xor(d1, 1, 64); q += __shfl_xor(q, 1, 64);
        d0 += __shfl_xor(d0, 2, 64); d1 += __shfl_xor(d1, 2, 64); q += __shfl_xor(q, 2, 64);
        d0 += __shfl_xor(d0, 4, 64); d1 += __shfl_xor(d1, 4, 64); q += __shfl_xor(q, 4, 64);
        d0 += __shfl_xor(d0, 8, 64); d1 += __shfl_xor(d1, 8, 64); q += __shfl_xor(q, 8, 64);
        if (sub == 0) {
            float n = fmaxf(sqrtf(q), 1e-12f);
            s0[r + grp] = d0 / n;
            s1[r + grp] = d1 / n;
        }
    }
    __syncthreads();

    // ---- rk: waves 0,1 -> row 0; waves 2,3 -> row 1.
    // Each wave covers 192 of the 384 k values (3 strided chunks of 64).
    const int base = (i0 >> 3) * GROUP;   // same for both rows
    const int row  = wave >> 1;
    const int half = wave & 1;
    const float* srow = row ? s1 : s0;

    float sb[GROUP];
    #pragma unroll
    for (int b = 0; b < GROUP; b++) sb[b] = srow[base + b];

    float acc8[GROUP];
    #pragma unroll
    for (int b = 0; b < GROUP; b++) acc8[b] = 0.0f;
    const int k0 = half * 192 + lane;
    #pragma unroll
    for (int j = 0; j < 3; j++) {
        float sk = srow[k0 + j * 64];
        #pragma unroll
        for (int b = 0; b < GROUP; b++)
            acc8[b] += temp_sigmoid_from_diff(sk - sb[b]);
    }
    #pragma unroll
    for (int b = 0; b < GROUP; b++) {
        float v = acc8[b];
        #pragma unroll
        for (int m = 32; m >= 1; m >>= 1) v += __shfl_xor(v, m, 64);
        acc8[b] = v;
    }
    if (lane == 0) {
        #pragma unroll
        for (int b = 0; b < GROUP; b++) part[row][half][b] = acc8[b];
    }
    __syncthreads();
    if (t < 16) rk2[t >> 3][t & 7] = part[t >> 3][0][t & 7] + part[t >> 3][1][t & 7];
    __syncthreads();

    // ---- pos part: wave 0 -> row 0, wave 1 -> row 1; lane = 8*b + c ----
    if (wave < 2) {
        const float* sp = wave ? s1 : s0;
        int b = lane >> 3, c = lane & 7;
        float v = temp_sigmoid_from_diff(sp[base + c] - sp[base + b]);
        v += __shfl_xor(v, 1, 64);
        v += __shfl_xor(v, 2, 64);
        v += __shfl_xor(v, 4, 64);   // lanes of group b hold pos_rk[b]
        float contrib = (c == 0) ? (v / rk2[wave][b]) : 0.0f;
        contrib += __shfl_xor(contrib, 8, 64);
        contrib += __shfl_xor(contrib, 16, 64);
        contrib += __shfl_xor(contrib, 32, 64);
        if (lane == 0) partials[i0 + wave] = contrib;  // unconditional -> poison-safe
    }
}

// Single block: sum 384 partials, finalize.
__global__ __launch_bounds__(256) void smoothap_finalize(
    const float* __restrict__ partials, float* __restrict__ out)
{
    __shared__ float red4[4];
    const int t = threadIdx.x;
    float v = partials[t];
    if (t < BATCH - 256) v += partials[t + 256];
    #pragma unroll
    for (int m = 32; m >= 1; m >>= 1) v += __shfl_xor(v, m, 64);
    if ((t & 63) == 0) red4[t >> 6] = v;
    __syncthreads();
    if (t == 0)
        out[0] = 1.0f - (red4[0] + red4[1] + red4[2] + red4[3])
                        / (float)(GROUP * BATCH);
}

extern "C" void kernel_launch(void* const* d_in, const int* in_sizes, int n_in,
                              void* d_out, int out_size, void* d_ws, size_t ws_size,
                              hipStream_t stream) {
    const float* preds   = (const float*)d_in[0];
    const float* gallery = (const float*)d_in[1];
    float* out = (float*)d_out;
    float* partials = (float*)d_ws;   // 384 floats, fully overwritten every call

    smoothap_main<<<BATCH / 2, 256, 0, stream>>>(preds, gallery, partials);
    smoothap_finalize<<<1, 256, 0, stream>>>(partials, out);
}

// Round 5
// 71.573 us; speedup vs baseline: 1.1463x; 1.1463x over previous
//
#include <hip/hip_runtime.h>
#include <math.h>

#define BATCH 384
#define FEAT 256
#define GROUP 8
// ANNEAL = 0.01 -> 1/temp = 100

__device__ __forceinline__ float temp_sigmoid_from_diff(float diff) {
    // reference: exponent = clip(-t/temp, -50, 50); 1/(1+exp(exponent))
    float e = fminf(fmaxf(-100.0f * diff, -50.0f), 50.0f);
    return 1.0f / (1.0f + __expf(e));
}

// ---------------------------------------------------------------------------
// One block per query row i.  (Round-3 configuration, resubmitted verbatim
// as a controlled repeat to measure cross-session variance: this exact
// source measured 73.3 us; the paired-rows variant measured 82.0 us.)
//
// Sim loop uses 16-lane clusters: each wave handles 4 gallery rows/iter,
// lanes (lane&15) hold contiguous 64B slices of one row -> every wave-level
// load instruction touches 16 contiguous cache lines (optimal).
// Gallery norms are fused into the dot loop (q accumulator), so no extra
// workspace beyond the 384 partials is needed.
// ---------------------------------------------------------------------------
__global__ __launch_bounds__(256) void smoothap_main(
    const float* __restrict__ preds, const float* __restrict__ gallery,
    float* __restrict__ partials)
{
    __shared__ float s[BATCH];
    __shared__ float rk[GROUP];
    __shared__ float part[4][GROUP];

    const int i    = blockIdx.x;
    const int t    = threadIdx.x;
    const int wave = t >> 6;
    const int lane = t & 63;
    const int sub  = lane & 15;   // position within 16-lane cluster
    const int grp  = lane >> 4;   // which of the 4 rows this cluster serves

    // ---- p-hat into registers: lane holds dims {sub*4 + 64*c .. +3}, c=0..3
    const float* prow = preds + i * FEAT + sub * 4;
    float4 p0 = *(const float4*)(prow);
    float4 p1 = *(const float4*)(prow + 64);
    float4 p2 = *(const float4*)(prow + 128);
    float4 p3 = *(const float4*)(prow + 192);

    float ssq = p0.x * p0.x + p0.y * p0.y + p0.z * p0.z + p0.w * p0.w
              + p1.x * p1.x + p1.y * p1.y + p1.z * p1.z + p1.w * p1.w
              + p2.x * p2.x + p2.y * p2.y + p2.z * p2.z + p2.w * p2.w
              + p3.x * p3.x + p3.y * p3.y + p3.z * p3.z + p3.w * p3.w;
    // each 16-lane cluster spans the full row -> reduce within cluster
    ssq += __shfl_xor(ssq, 1, 64);
    ssq += __shfl_xor(ssq, 2, 64);
    ssq += __shfl_xor(ssq, 4, 64);
    ssq += __shfl_xor(ssq, 8, 64);
    const float pn = fmaxf(sqrtf(ssq), 1e-12f);
    p0.x /= pn; p0.y /= pn; p0.z /= pn; p0.w /= pn;
    p1.x /= pn; p1.y /= pn; p1.z /= pn; p1.w /= pn;
    p2.x /= pn; p2.y /= pn; p2.z /= pn; p2.w /= pn;
    p3.x /= pn; p3.y /= pn; p3.z /= pn; p3.w /= pn;

    // ---- sim row: wave w computes s[k] for k in [w*96, w*96+96), 4 rows/iter
    const int r_end = wave * 96 + 96;
    for (int r = wave * 96; r < r_end; r += 4) {
        const float* g = gallery + (r + grp) * FEAT + sub * 4;
        float4 a = *(const float4*)(g);
        float4 b = *(const float4*)(g + 64);
        float4 c = *(const float4*)(g + 128);
        float4 d = *(const float4*)(g + 192);
        float dot = p0.x * a.x + p0.y * a.y + p0.z * a.z + p0.w * a.w
                  + p1.x * b.x + p1.y * b.y + p1.z * b.z + p1.w * b.w
                  + p2.x * c.x + p2.y * c.y + p2.z * c.z + p2.w * c.w
                  + p3.x * d.x + p3.y * d.y + p3.z * d.z + p3.w * d.w;
        float q   = a.x * a.x + a.y * a.y + a.z * a.z + a.w * a.w
                  + b.x * b.x + b.y * b.y + b.z * b.z + b.w * b.w
                  + c.x * c.x + c.y * c.y + c.z * c.z + c.w * c.w
                  + d.x * d.x + d.y * d.y + d.z * d.z + d.w * d.w;
        dot += __shfl_xor(dot, 1, 64);  q += __shfl_xor(q, 1, 64);
        dot += __shfl_xor(dot, 2, 64);  q += __shfl_xor(q, 2, 64);
        dot += __shfl_xor(dot, 4, 64);  q += __shfl_xor(q, 4, 64);
        dot += __shfl_xor(dot, 8, 64);  q += __shfl_xor(q, 8, 64);
        if (sub == 0) s[r + grp] = dot / fmaxf(sqrtf(q), 1e-12f);
    }
    __syncthreads();

    const int base = (i >> 3) * GROUP;  // start of this id's diagonal block
    float sb[GROUP];
    #pragma unroll
    for (int b = 0; b < GROUP; b++) sb[b] = s[base + b];

    // ---- rk[b] = sum_k sigmoid_t(s[k] - s[base+b]) ----
    float acc8[GROUP];
    #pragma unroll
    for (int b = 0; b < GROUP; b++) acc8[b] = 0.0f;
    for (int k = t; k < BATCH; k += 256) {
        float sk = s[k];
        #pragma unroll
        for (int b = 0; b < GROUP; b++)
            acc8[b] += temp_sigmoid_from_diff(sk - sb[b]);
    }
    #pragma unroll
    for (int b = 0; b < GROUP; b++) {
        float v = acc8[b];
        #pragma unroll
        for (int m = 32; m >= 1; m >>= 1) v += __shfl_xor(v, m, 64);
        acc8[b] = v;
    }
    if ((t & 63) == 0) {
        #pragma unroll
        for (int b = 0; b < GROUP; b++) part[t >> 6][b] = acc8[b];
    }
    __syncthreads();
    if (t < GROUP) rk[t] = part[0][t] + part[1][t] + part[2][t] + part[3][t];
    __syncthreads();

    // ---- pos part on wave 0: lane = 8*b + c ----
    if (t < 64) {
        int b = t >> 3, c = t & 7;
        float v = temp_sigmoid_from_diff(s[base + c] - s[base + b]);
        v += __shfl_xor(v, 1, 64);
        v += __shfl_xor(v, 2, 64);
        v += __shfl_xor(v, 4, 64);   // lanes of group b hold pos_rk[b]
        float contrib = (c == 0) ? (v / rk[b]) : 0.0f;
        contrib += __shfl_xor(contrib, 8, 64);
        contrib += __shfl_xor(contrib, 16, 64);
        contrib += __shfl_xor(contrib, 32, 64);
        if (t == 0) partials[i] = contrib;   // unconditional write -> poison-safe
    }
}

// Single block: sum 384 partials, finalize.
__global__ __launch_bounds__(256) void smoothap_finalize(
    const float* __restrict__ partials, float* __restrict__ out)
{
    __shared__ float red4[4];
    const int t = threadIdx.x;
    float v = partials[t];
    if (t < BATCH - 256) v += partials[t + 256];
    #pragma unroll
    for (int m = 32; m >= 1; m >>= 1) v += __shfl_xor(v, m, 64);
    if ((t & 63) == 0) red4[t >> 6] = v;
    __syncthreads();
    if (t == 0)
        out[0] = 1.0f - (red4[0] + red4[1] + red4[2] + red4[3])
                        / (float)(GROUP * BATCH);
}

extern "C" void kernel_launch(void* const* d_in, const int* in_sizes, int n_in,
                              void* d_out, int out_size, void* d_ws, size_t ws_size,
                              hipStream_t stream) {
    const float* preds   = (const float*)d_in[0];
    const float* gallery = (const float*)d_in[1];
    float* out = (float*)d_out;
    float* partials = (float*)d_ws;   // 384 floats, fully overwritten every call

    smoothap_main<<<BATCH, 256, 0, stream>>>(preds, gallery, partials);
    smoothap_finalize<<<1, 256, 0, stream>>>(partials, out);
}

// Round 6
// 67.342 us; speedup vs baseline: 1.2183x; 1.0628x over previous
//
#include <hip/hip_runtime.h>
#include <math.h>

#define BATCH 384
#define FEAT 256
#define GROUP 8
// ANNEAL = 0.01 -> 1/temp = 100

__device__ __forceinline__ float temp_sigmoid_from_diff(float diff) {
    // reference: exponent = clip(-t/temp, -50, 50); 1/(1+exp(exponent))
    float e = fminf(fmaxf(-100.0f * diff, -50.0f), 50.0f);
    return 1.0f / (1.0f + __expf(e));
}

// ---------------------------------------------------------------------------
// One block per query row i, 512 threads (8 waves).
// vs the 256-thread round-3/5 version (71.6/73.3 us): halves the per-wave
// sim critical path (12 iters instead of 24) and doubles waves/SIMD
// (1.5 -> 3) for latency hiding, at identical total work and identical
// per-value arithmetic (absmax stayed 0 across all prior variants).
//
// Sim loop uses 16-lane clusters: each wave handles 4 gallery rows/iter,
// lanes (lane&15) hold contiguous 64B slices of one row -> every wave-level
// load instruction touches 16 contiguous cache lines (optimal).
// Gallery norms are fused into the dot loop (q accumulator).
// ---------------------------------------------------------------------------
__global__ __launch_bounds__(512) void smoothap_main(
    const float* __restrict__ preds, const float* __restrict__ gallery,
    float* __restrict__ partials)
{
    __shared__ float s[BATCH];
    __shared__ float rk[GROUP];
    __shared__ float part[6][GROUP];

    const int i    = blockIdx.x;
    const int t    = threadIdx.x;
    const int wave = t >> 6;      // 0..7
    const int lane = t & 63;
    const int sub  = lane & 15;   // position within 16-lane cluster
    const int grp  = lane >> 4;   // which of the 4 rows this cluster serves

    // ---- p-hat into registers: lane holds dims {sub*4 + 64*c .. +3}, c=0..3
    const float* prow = preds + i * FEAT + sub * 4;
    float4 p0 = *(const float4*)(prow);
    float4 p1 = *(const float4*)(prow + 64);
    float4 p2 = *(const float4*)(prow + 128);
    float4 p3 = *(const float4*)(prow + 192);

    float ssq = p0.x * p0.x + p0.y * p0.y + p0.z * p0.z + p0.w * p0.w
              + p1.x * p1.x + p1.y * p1.y + p1.z * p1.z + p1.w * p1.w
              + p2.x * p2.x + p2.y * p2.y + p2.z * p2.z + p2.w * p2.w
              + p3.x * p3.x + p3.y * p3.y + p3.z * p3.z + p3.w * p3.w;
    // each 16-lane cluster spans the full row -> reduce within cluster
    ssq += __shfl_xor(ssq, 1, 64);
    ssq += __shfl_xor(ssq, 2, 64);
    ssq += __shfl_xor(ssq, 4, 64);
    ssq += __shfl_xor(ssq, 8, 64);
    const float pn = fmaxf(sqrtf(ssq), 1e-12f);
    p0.x /= pn; p0.y /= pn; p0.z /= pn; p0.w /= pn;
    p1.x /= pn; p1.y /= pn; p1.z /= pn; p1.w /= pn;
    p2.x /= pn; p2.y /= pn; p2.z /= pn; p2.w /= pn;
    p3.x /= pn; p3.y /= pn; p3.z /= pn; p3.w /= pn;

    // ---- sim row: wave w computes s[k] for k in [w*48, w*48+48), 4 rows/iter
    const int r_end = wave * 48 + 48;
    #pragma unroll 2
    for (int r = wave * 48; r < r_end; r += 4) {
        const float* g = gallery + (r + grp) * FEAT + sub * 4;
        float4 a = *(const float4*)(g);
        float4 b = *(const float4*)(g + 64);
        float4 c = *(const float4*)(g + 128);
        float4 d = *(const float4*)(g + 192);
        float dot = p0.x * a.x + p0.y * a.y + p0.z * a.z + p0.w * a.w
                  + p1.x * b.x + p1.y * b.y + p1.z * b.z + p1.w * b.w
                  + p2.x * c.x + p2.y * c.y + p2.z * c.z + p2.w * c.w
                  + p3.x * d.x + p3.y * d.y + p3.z * d.z + p3.w * d.w;
        float q   = a.x * a.x + a.y * a.y + a.z * a.z + a.w * a.w
                  + b.x * b.x + b.y * b.y + b.z * b.z + b.w * b.w
                  + c.x * c.x + c.y * c.y + c.z * c.z + c.w * c.w
                  + d.x * d.x + d.y * d.y + d.z * d.z + d.w * d.w;
        dot += __shfl_xor(dot, 1, 64);  q += __shfl_xor(q, 1, 64);
        dot += __shfl_xor(dot, 2, 64);  q += __shfl_xor(q, 2, 64);
        dot += __shfl_xor(dot, 4, 64);  q += __shfl_xor(q, 4, 64);
        dot += __shfl_xor(dot, 8, 64);  q += __shfl_xor(q, 8, 64);
        if (sub == 0) s[r + grp] = dot / fmaxf(sqrtf(q), 1e-12f);
    }
    __syncthreads();

    const int base = (i >> 3) * GROUP;  // start of this id's diagonal block

    // ---- rk[b] = sum_k sigmoid_t(s[k] - s[base+b]) ----
    // 384 k-values over waves 0..5, exactly one k per thread.
    if (wave < 6) {
        float sb[GROUP];
        #pragma unroll
        for (int b = 0; b < GROUP; b++) sb[b] = s[base + b];

        const float sk = s[t];
        float acc8[GROUP];
        #pragma unroll
        for (int b = 0; b < GROUP; b++)
            acc8[b] = temp_sigmoid_from_diff(sk - sb[b]);
        #pragma unroll
        for (int b = 0; b < GROUP; b++) {
            float v = acc8[b];
            #pragma unroll
            for (int m = 32; m >= 1; m >>= 1) v += __shfl_xor(v, m, 64);
            acc8[b] = v;
        }
        if (lane == 0) {
            #pragma unroll
            for (int b = 0; b < GROUP; b++) part[wave][b] = acc8[b];
        }
    }
    __syncthreads();
    if (t < GROUP)
        rk[t] = part[0][t] + part[1][t] + part[2][t]
              + part[3][t] + part[4][t] + part[5][t];
    __syncthreads();

    // ---- pos part on wave 0: lane = 8*b + c ----
    if (t < 64) {
        int b = t >> 3, c = t & 7;
        float v = temp_sigmoid_from_diff(s[base + c] - s[base + b]);
        v += __shfl_xor(v, 1, 64);
        v += __shfl_xor(v, 2, 64);
        v += __shfl_xor(v, 4, 64);   // lanes of group b hold pos_rk[b]
        float contrib = (c == 0) ? (v / rk[b]) : 0.0f;
        contrib += __shfl_xor(contrib, 8, 64);
        contrib += __shfl_xor(contrib, 16, 64);
        contrib += __shfl_xor(contrib, 32, 64);
        if (t == 0) partials[i] = contrib;   // unconditional write -> poison-safe
    }
}

// Single block: sum 384 partials, finalize.
__global__ __launch_bounds__(256) void smoothap_finalize(
    const float* __restrict__ partials, float* __restrict__ out)
{
    __shared__ float red4[4];
    const int t = threadIdx.x;
    float v = partials[t];
    if (t < BATCH - 256) v += partials[t + 256];
    #pragma unroll
    for (int m = 32; m >= 1; m >>= 1) v += __shfl_xor(v, m, 64);
    if ((t & 63) == 0) red4[t >> 6] = v;
    __syncthreads();
    if (t == 0)
        out[0] = 1.0f - (red4[0] + red4[1] + red4[2] + red4[3])
                        / (float)(GROUP * BATCH);
}

extern "C" void kernel_launch(void* const* d_in, const int* in_sizes, int n_in,
                              void* d_out, int out_size, void* d_ws, size_t ws_size,
                              hipStream_t stream) {
    const float* preds   = (const float*)d_in[0];
    const float* gallery = (const float*)d_in[1];
    float* out = (float*)d_out;
    float* partials = (float*)d_ws;   // 384 floats, fully overwritten every call

    smoothap_main<<<BATCH, 512, 0, stream>>>(preds, gallery, partials);
    smoothap_finalize<<<1, 256, 0, stream>>>(partials, out);
}